// Round 4
// baseline (624.575 us; speedup 1.0000x reference)
//
#include <hip/hip_runtime.h>
#include <math.h>

#define N_RAYS 2048
#define NSAMP  256
#define NPTS   (N_RAYS * NSAMP)
#define NCHUNK (NPTS / 64)
#define GRIDN  128
#define G2     (GRIDN * GRIDN)
#define G3     (GRIDN * GRIDN * GRIDN)
#define APPC   27
#define CHP    28            // padded channels in transposed volume
#define FEATC  128
#define K1PAD  160           // 150 padded to 160 (5 k-tiles of 32)
#define ASTR   168           // A_lds k-stride
#define HSTR   136           // h1_lds k-stride
#define H2STR  130           // h2 stride (aliases A_lds) — odd dword stride: conflict-free

typedef __attribute__((ext_vector_type(8))) short short8;
typedef __attribute__((ext_vector_type(4))) float float4v;

__device__ __forceinline__ unsigned short f2bf(float f) {
  unsigned int u = __float_as_uint(f);
  return (unsigned short)((u + 0x7FFFu + ((u >> 16) & 1u)) >> 16);
}
__device__ __forceinline__ float bf2f(unsigned short u) {
  return __uint_as_float(((unsigned int)u) << 16);
}

__device__ __forceinline__ void corner_setup_xyz(float cx, float cy, float cz,
                                                 int& x0, int& y0, int& z0,
                                                 int& ibase, float* w8) {
  float x = (cx + 1.0f) * 0.5f * 127.0f;
  float y = (cy + 1.0f) * 0.5f * 127.0f;
  float z = (cz + 1.0f) * 0.5f * 127.0f;
  float x0f = fminf(fmaxf(floorf(x), 0.0f), 126.0f);
  float y0f = fminf(fmaxf(floorf(y), 0.0f), 126.0f);
  float z0f = fminf(fmaxf(floorf(z), 0.0f), 126.0f);
  x0 = (int)x0f; y0 = (int)y0f; z0 = (int)z0f;
  float fx = x - x0f, fy = y - y0f, fz = z - z0f;
  float gx = 1.0f - fx, gy = 1.0f - fy, gz = 1.0f - fz;
  ibase = (z0 * GRIDN + y0) * GRIDN + x0;
  w8[0] = gz * gy * gx; w8[1] = gz * gy * fx;
  w8[2] = gz * fy * gx; w8[3] = gz * fy * fx;
  w8[4] = fz * gy * gx; w8[5] = fz * gy * fx;
  w8[6] = fz * fy * gx; w8[7] = fz * fy * fx;
}

// ---------------- ray kernel: alpha + wave-scan cumprod -> weights, acc, worklist, AABB
__global__ __launch_bounds__(256)
void ray_kernel(const float* __restrict__ rays_o, const float* __restrict__ rays_d,
                const float* __restrict__ dvol,
                float* __restrict__ weights_ws, float* __restrict__ acc_ws,
                int* __restrict__ count, int* __restrict__ worklist,
                int* __restrict__ bounds) {   // [xmin,ymin,zmin,xmax,ymax,zmax]
  int r = blockIdx.x, s = threadIdx.x;
  int lane = s & 63, wv = s >> 6;
  float ox = rays_o[r*3+0], oy = rays_o[r*3+1], oz = rays_o[r*3+2];
  float dx = rays_d[r*3+0], dy = rays_d[r*3+1], dz = rays_d[r*3+2];
  float inv = rsqrtf(dx*dx + dy*dy + dz*dz);
  dx *= inv; dy *= inv; dz *= inv;
  float z = 2.0f + (4.0f / 255.0f) * (float)s;
  float px = ox + dx * z, py = oy + dy * z, pz = oz + dz * z;
  float cx = fminf(fmaxf((px + 1.5f) * (2.0f/3.0f) - 1.0f, -1.0f), 1.0f);
  float cy = fminf(fmaxf((py + 1.5f) * (2.0f/3.0f) - 1.0f, -1.0f), 1.0f);
  float cz = fminf(fmaxf((pz + 1.5f) * (2.0f/3.0f) - 1.0f, -1.0f), 1.0f);
  int x0, y0, z0, ibase; float w8[8];
  corner_setup_xyz(cx, cy, cz, x0, y0, z0, ibase, w8);
  float sf = dvol[ibase]            * w8[0] + dvol[ibase + 1]            * w8[1]
           + dvol[ibase + GRIDN]    * w8[2] + dvol[ibase + GRIDN + 1]    * w8[3]
           + dvol[ibase + G2]       * w8[4] + dvol[ibase + G2 + 1]       * w8[5]
           + dvol[ibase + G2+GRIDN] * w8[6] + dvol[ibase + G2+GRIDN+1]   * w8[7];
  float xv = sf - 10.0f;
  float sp = (xv > 0.0f) ? (xv + log1pf(expf(-xv))) : log1pf(expf(xv));
  float alpha = 1.0f - expf(-sp * (100.0f / 255.0f));

  // wave-level inclusive prefix product of (1 - a + 1e-10)
  float tt = 1.0f - alpha + 1e-10f;
  float p = tt;
  #pragma unroll
  for (int d = 1; d < 64; d <<= 1) {
    float v = __shfl_up(p, d);
    if (lane >= d) p *= v;
  }
  __shared__ float wtot[4], wacc[4];
  if (lane == 63) wtot[wv] = p;
  __syncthreads();
  float pref = 1.0f;
  #pragma unroll
  for (int w2i = 0; w2i < 3; ++w2i) if (w2i < wv) pref *= wtot[w2i];
  float ex = __shfl_up(p, 1);
  if (lane == 0) ex = 1.0f;
  float T = pref * ex;
  float wgt = alpha * T;
  weights_ws[r * NSAMP + s] = wgt;

  // wave reduce: weight sum + voxel AABB
  float sum = wgt;
  int mnx = x0, mny = y0, mnz = z0, mxx = x0, mxy = y0, mxz = z0;
  #pragma unroll
  for (int d = 32; d; d >>= 1) {
    sum += __shfl_xor(sum, d);
    mnx = min(mnx, __shfl_xor(mnx, d)); mxx = max(mxx, __shfl_xor(mxx, d));
    mny = min(mny, __shfl_xor(mny, d)); mxy = max(mxy, __shfl_xor(mxy, d));
    mnz = min(mnz, __shfl_xor(mnz, d)); mxz = max(mxz, __shfl_xor(mxz, d));
  }
  if (lane == 0) {
    wacc[wv] = sum;
    if (sum >= 1e-5f) {                    // live chunk -> enqueue + AABB
      int pos = atomicAdd(count, 1);
      worklist[pos] = r * 4 + wv;
      atomicMin(&bounds[0], mnx); atomicMax(&bounds[3], mxx + 1);
      atomicMin(&bounds[1], mny); atomicMax(&bounds[4], mxy + 1);
      atomicMin(&bounds[2], mnz); atomicMax(&bounds[5], mxz + 1);
    }
  }
  __syncthreads();
  if (s == 0) acc_ws[r] = wacc[0] + wacc[1] + wacc[2] + wacc[3];
}

// ---------------- transpose app volume (AABB-restricted):
// [27][z][y][x] f32 -> [z][y][x][28] bf16, 2 voxels per thread
__global__ __launch_bounds__(256)
void transpose_kernel(const float* __restrict__ avol, unsigned short* __restrict__ appT,
                      const int* __restrict__ bounds) {
  int vblk = blockIdx.x * 512;            // block covers one z, 4 y-rows
  int zb = vblk >> 14;
  int yb = (vblk & 16383) >> 7;           // block covers y in [yb, yb+3]
  int zmin = bounds[2], zmax = bounds[5];
  int ymin = bounds[1], ymax = bounds[4];
  if (zb < zmin || zb > zmax) return;
  if (yb + 3 < ymin || yb > ymax) return;
  int v0 = vblk + threadIdx.x * 2;
  int y = (v0 & 16383) >> 7;
  int x = v0 & 127;
  if (y < ymin || y > ymax) return;
  int xmin = bounds[0], xmax = bounds[3];
  if (x + 1 < xmin || x > xmax) return;

  float2 v[APPC];
  #pragma unroll
  for (int c = 0; c < APPC; ++c) v[c] = *(const float2*)&avol[(size_t)c * G3 + v0];
  unsigned short* dst = appT + (size_t)v0 * CHP;
  #pragma unroll
  for (int i = 0; i < 7; ++i) {
    ushort4 o;
    o.x = f2bf(v[4*i+0].x); o.y = f2bf(v[4*i+1].x);
    o.z = (4*i+2 < APPC) ? f2bf(v[4*i+2].x) : (unsigned short)0;
    o.w = (4*i+3 < APPC) ? f2bf(v[4*i+3].x) : (unsigned short)0;
    *(ushort4*)&dst[4*i] = o;
  }
  #pragma unroll
  for (int i = 0; i < 7; ++i) {
    ushort4 o;
    o.x = f2bf(v[4*i+0].y); o.y = f2bf(v[4*i+1].y);
    o.z = (4*i+2 < APPC) ? f2bf(v[4*i+2].y) : (unsigned short)0;
    o.w = (4*i+3 < APPC) ? f2bf(v[4*i+3].y) : (unsigned short)0;
    *(ushort4*)&dst[CHP + 4*i] = o;
  }
}

// ---------------- weight prep
__global__ __launch_bounds__(256)
void prep_weights(const float* __restrict__ w1, const float* __restrict__ w2,
                  unsigned short* __restrict__ w1T, unsigned short* __restrict__ w2T) {
  int t = blockIdx.x * 256 + threadIdx.x;
  if (t < 128 * K1PAD) {
    int n = t / K1PAD, k = t - n * K1PAD;
    w1T[t] = (k < 150) ? f2bf(w1[k * 128 + n]) : (unsigned short)0;
  } else {
    int i = t - 128 * K1PAD;
    if (i < 128 * 128) {
      int n = i >> 7, k = i & 127;
      w2T[i] = f2bf(w2[k * 128 + n]);
    }
  }
}

// ---------------- persistent shade over compacted worklist
template <bool USET>
__global__ __launch_bounds__(256)
void shade_kernel(const float* __restrict__ rays_o, const float* __restrict__ rays_d,
                  const float* __restrict__ avol, const unsigned short* __restrict__ appT,
                  const unsigned short* __restrict__ w1T, const unsigned short* __restrict__ w2T,
                  const float* __restrict__ b1, const float* __restrict__ b2,
                  const float* __restrict__ w3, const float* __restrict__ b3,
                  const float* __restrict__ weights_ws, float* __restrict__ rgb_accum,
                  const int* __restrict__ count, int* __restrict__ work_ctr,
                  const int* __restrict__ worklist) {
  __shared__ unsigned short A_lds[64 * ASTR];   // reused as h2 (stride 130)
  __shared__ unsigned short h1_lds[64 * HSTR];
  __shared__ int s_idx, s_n;

  int t = threadIdx.x;
  int lane = t & 63, wv = t >> 6;

  if (t == 0) s_n = *count;

  for (;;) {
    __syncthreads();
    if (t == 0) s_idx = atomicAdd(work_ctr, 1);
    __syncthreads();
    if (s_idx >= s_n) break;
    int chunk = worklist[s_idx];
    int gp0 = chunk * 64;
    int r = gp0 >> 8;

    // ---- gather + positional encoding ----
    {
      int q = t & 3, pt = t >> 2;
      int gp = gp0 + pt, s = gp & 255;
      float ox = rays_o[r*3+0], oy = rays_o[r*3+1], oz = rays_o[r*3+2];
      float dx = rays_d[r*3+0], dy = rays_d[r*3+1], dz = rays_d[r*3+2];
      float inv = rsqrtf(dx*dx + dy*dy + dz*dz);
      dx *= inv; dy *= inv; dz *= inv;
      float z = 2.0f + (4.0f / 255.0f) * (float)s;
      float px = ox + dx * z, py = oy + dy * z, pz = oz + dz * z;
      float cx = fminf(fmaxf((px + 1.5f) * (2.0f/3.0f) - 1.0f, -1.0f), 1.0f);
      float cy = fminf(fmaxf((py + 1.5f) * (2.0f/3.0f) - 1.0f, -1.0f), 1.0f);
      float cz = fminf(fmaxf((pz + 1.5f) * (2.0f/3.0f) - 1.0f, -1.0f), 1.0f);
      int x0, y0, z0, ibase; float w8[8];
      corner_setup_xyz(cx, cy, cz, x0, y0, z0, ibase, w8);

      int vi = ibase + (q >> 1) * G2 + (q & 1) * GRIDN;
      float wA = w8[2*q], wB = w8[2*q+1];
      float part[27];
      if (USET) {
        const ushort4* c0 = (const ushort4*)(appT + (size_t)vi * CHP);
        const ushort4* c1 = (const ushort4*)(appT + (size_t)(vi + 1) * CHP);
        ushort4 a[7], b[7];
        #pragma unroll
        for (int i = 0; i < 7; ++i) { a[i] = c0[i]; b[i] = c1[i]; }
        #pragma unroll
        for (int c = 0; c < 27; ++c) {
          unsigned short ua = (&a[c >> 2].x)[c & 3];
          unsigned short ub = (&b[c >> 2].x)[c & 3];
          part[c] = wA * bf2f(ua) + wB * bf2f(ub);
        }
      } else {
        #pragma unroll
        for (int c = 0; c < 27; ++c) {
          const float* base = avol + (size_t)c * G3 + vi;
          part[c] = wA * base[0] + wB * base[1];
        }
      }
      #pragma unroll
      for (int c = 0; c < 27; ++c) {
        float v = part[c];
        v += __shfl_xor(v, 1);
        v += __shfl_xor(v, 2);
        part[c] = v;
      }
      float f[7];
      #pragma unroll
      for (int j = 0; j < 7; ++j) {
        float vlo = (q & 1) ? part[7 + j] : part[j];
        float vhi = (q & 1) ? part[(21 + j < 27) ? 21 + j : 26] : part[14 + j];
        f[j] = (q & 2) ? vhi : vlo;
      }
      unsigned short* Arow = A_lds + pt * ASTR;
      int cbase = 7 * q;
      #pragma unroll
      for (int j = 0; j < 7; ++j) {
        int c = cbase + j;
        if (c < 27) {
          float fv = f[j];
          Arow[c] = f2bf(fv);
          float s1 = __sinf(fv),      c1 = __cosf(fv);
          float s2 = __sinf(2.0f*fv), c2 = __cosf(2.0f*fv);
          Arow[30 + 2*c] = f2bf(s1); Arow[31 + 2*c] = f2bf(s2);
          Arow[84 + 2*c] = f2bf(c1); Arow[85 + 2*c] = f2bf(c2);
        }
      }
      if (q == 3) {
        float vd[3] = {dx, dy, dz};
        #pragma unroll
        for (int d = 0; d < 3; ++d) {
          Arow[27 + d] = f2bf(vd[d]);
          float s1 = __sinf(vd[d]),      c1 = __cosf(vd[d]);
          float s2 = __sinf(2.0f*vd[d]), c2 = __cosf(2.0f*vd[d]);
          Arow[138 + 2*d] = f2bf(s1); Arow[139 + 2*d] = f2bf(s2);
          Arow[144 + 2*d] = f2bf(c1); Arow[145 + 2*d] = f2bf(c2);
        }
      }
      if (q == 1) {
        #pragma unroll
        for (int i = 0; i < 5; ++i) *(unsigned int*)&Arow[150 + 2*i] = 0u;
      }
    }
    __syncthreads();

    // ---- MFMA MLP ----
    int nlo = lane & 15;
    int koff = (lane >> 4) * 8;
    int mrow = wv * 16 + nlo;

    short8 a1[5];
    #pragma unroll
    for (int kt = 0; kt < 5; ++kt)
      a1[kt] = *(const short8*)&A_lds[mrow * ASTR + kt * 32 + koff];
    #pragma unroll
    for (int nt = 0; nt < 8; ++nt) {
      float4v acc = {0.f, 0.f, 0.f, 0.f};
      #pragma unroll
      for (int kt = 0; kt < 5; ++kt) {
        short8 b = *(const short8*)&w1T[(nt * 16 + nlo) * K1PAD + kt * 32 + koff];
        acc = __builtin_amdgcn_mfma_f32_16x16x32_bf16(a1[kt], b, acc, 0, 0, 0);
      }
      float bv = b1[nt * 16 + nlo];
      #pragma unroll
      for (int rg = 0; rg < 4; ++rg) {
        int m = wv * 16 + (lane >> 4) * 4 + rg;
        float hv = fmaxf(acc[rg] + bv, 0.0f);
        h1_lds[m * HSTR + nt * 16 + nlo] = f2bf(hv);
      }
    }
    __syncthreads();

    short8 a2[4];
    #pragma unroll
    for (int kt = 0; kt < 4; ++kt)
      a2[kt] = *(const short8*)&h1_lds[mrow * HSTR + kt * 32 + koff];
    unsigned short* h2 = A_lds;
    #pragma unroll
    for (int nt = 0; nt < 8; ++nt) {
      float4v acc = {0.f, 0.f, 0.f, 0.f};
      #pragma unroll
      for (int kt = 0; kt < 4; ++kt) {
        short8 b = *(const short8*)&w2T[(nt * 16 + nlo) * FEATC + kt * 32 + koff];
        acc = __builtin_amdgcn_mfma_f32_16x16x32_bf16(a2[kt], b, acc, 0, 0, 0);
      }
      float bv = b2[nt * 16 + nlo];
      #pragma unroll
      for (int rg = 0; rg < 4; ++rg) {
        int m = wv * 16 + (lane >> 4) * 4 + rg;
        float hv = fmaxf(acc[rg] + bv, 0.0f);
        h2[m * H2STR + nt * 16 + nlo] = f2bf(hv);
      }
    }
    __syncthreads();

    // ---- layer 3 (128 -> 3) + sigmoid + in-wave weighted reduce ----
    if (wv < 3) {
      int j = wv, pp = lane;
      const unsigned short* h2row = h2 + pp * H2STR;
      float sum = b3[j];
      #pragma unroll
      for (int k = 0; k < FEATC; k += 4) {
        ushort4 hv = *(const ushort4*)&h2row[k];
        sum += bf2f(hv.x) * w3[(k+0)*3 + j] + bf2f(hv.y) * w3[(k+1)*3 + j]
             + bf2f(hv.z) * w3[(k+2)*3 + j] + bf2f(hv.w) * w3[(k+3)*3 + j];
      }
      float val = (1.0f / (1.0f + __expf(-sum))) * weights_ws[gp0 + pp];
      #pragma unroll
      for (int d = 32; d; d >>= 1) val += __shfl_xor(val, d);
      if (pp == 0) atomicAdd(&rgb_accum[r * 3 + j], val);
    }
  }
}

__global__ void finish_kernel(const float* __restrict__ rgb_accum,
                              const float* __restrict__ acc_ws,
                              float* __restrict__ out) {
  int i = blockIdx.x * blockDim.x + threadIdx.x;
  if (i < N_RAYS * 3) {
    int r = i / 3;
    float v = rgb_accum[i] + 1.0f - acc_ws[r];
    out[i] = fminf(fmaxf(v, 0.0f), 1.0f);
  }
}

extern "C" void kernel_launch(void* const* d_in, const int* in_sizes, int n_in,
                              void* d_out, int out_size, void* d_ws, size_t ws_size,
                              hipStream_t stream) {
  const float* rays_o = (const float*)d_in[0];
  const float* rays_d = (const float*)d_in[1];
  const float* dvol   = (const float*)d_in[2];
  const float* avol   = (const float*)d_in[3];
  const float* w1     = (const float*)d_in[4];
  const float* b1     = (const float*)d_in[5];
  const float* w2     = (const float*)d_in[6];
  const float* b2     = (const float*)d_in[7];
  const float* w3     = (const float*)d_in[8];
  const float* b3     = (const float*)d_in[9];
  float* out = (float*)d_out;

  float* weights_ws = (float*)d_ws;                         // NPTS
  float* acc_ws     = weights_ws + NPTS;                    // 2048
  float* rgb_accum  = acc_ws + N_RAYS;                      // 6144
  int*   count      = (int*)(rgb_accum + N_RAYS * 3);       // 1
  int*   work_ctr   = count + 1;                            // 1
  int*   bounds     = work_ctr + 1;                         // 6
  int*   worklist   = bounds + 6;                           // NCHUNK
  unsigned short* w1T = (unsigned short*)(worklist + NCHUNK);
  unsigned short* w2T = w1T + 128 * K1PAD;
  unsigned short* appT = w2T + 128 * 128;

  size_t fixed_bytes = (size_t)(NPTS + N_RAYS + N_RAYS * 3 + 8 + NCHUNK) * 4
                     + (size_t)(128 * K1PAD + 128 * 128) * 2;
  size_t need = fixed_bytes + (size_t)G3 * CHP * 2;
  bool uset = ws_size >= need;

  // zero rgb_accum + count + work_ctr; bounds mins -> large, maxs -> 0
  hipMemsetAsync(rgb_accum, 0, (N_RAYS * 3 + 2) * sizeof(float), stream);
  hipMemsetAsync(bounds, 0x7f, 3 * sizeof(int), stream);
  hipMemsetAsync(bounds + 3, 0, 3 * sizeof(int), stream);
  prep_weights<<<(128 * K1PAD + 128 * 128 + 255) / 256, 256, 0, stream>>>(w1, w2, w1T, w2T);
  ray_kernel<<<N_RAYS, 256, 0, stream>>>(rays_o, rays_d, dvol, weights_ws, acc_ws,
                                         count, worklist, bounds);
  if (uset) {
    transpose_kernel<<<G3 / 512, 256, 0, stream>>>(avol, appT, bounds);
    shade_kernel<true><<<1024, 256, 0, stream>>>(rays_o, rays_d, avol, appT, w1T, w2T,
                                                 b1, b2, w3, b3, weights_ws, rgb_accum,
                                                 count, work_ctr, worklist);
  } else {
    shade_kernel<false><<<1024, 256, 0, stream>>>(rays_o, rays_d, avol, appT, w1T, w2T,
                                                  b1, b2, w3, b3, weights_ws, rgb_accum,
                                                  count, work_ctr, worklist);
  }
  finish_kernel<<<(N_RAYS * 3 + 255) / 256, 256, 0, stream>>>(rgb_accum, acc_ws, out);
}